// Round 1
// baseline (5617.470 us; speedup 1.0000x reference)
//
#include <hip/hip_runtime.h>
#include <hip/hip_bf16.h>

#define HD    256
#define TENC  15
#define PLEN  45
#define MROW  64
#define NTHR  512

typedef __attribute__((ext_vector_type(4))) float f32x4;
typedef __attribute__((ext_vector_type(8))) short bf16x8;

#define MFMA16 __builtin_amdgcn_mfma_f32_16x16x32_bf16

__device__ __forceinline__ unsigned short f2bf(float f) {
    union { float f; unsigned int u; } v; v.f = f;
    unsigned int r = v.u + 0x7FFF + ((v.u >> 16) & 1);  // RNE
    return (unsigned short)(r >> 16);
}
__device__ __forceinline__ float bf2f(unsigned short u) {
    union { unsigned int u; float f; } v; v.u = ((unsigned int)u) << 16;
    return v.f;
}

__global__ void cvt_bf16_kernel(const float* __restrict__ src,
                                unsigned short* __restrict__ dst, int n) {
    int i = blockIdx.x * blockDim.x + threadIdx.x;
    if (i < n) dst[i] = f2bf(src[i]);
}

// Swizzled byte offset into a [MROW][HD] bf16 LDS tile (row stride 512B).
// 16B chunk index is XORed with row&7 -> breaks the 16-way bank conflict on
// ds_read_b128 at stride 512B (G4).
__device__ __forceinline__ int swz(int row, int col) {
    return row * 512 + ((((col >> 3) ^ (row & 7)) << 4) | ((col & 7) << 1));
}

__global__ __launch_bounds__(NTHR, 2) void gru_main(
    const float* __restrict__ x,
    const float* __restrict__ eW, const float* __restrict__ eb,
    const unsigned short* __restrict__ encWih, const unsigned short* __restrict__ encWhh,
    const float* __restrict__ enc_bih, const float* __restrict__ enc_bhh,
    const unsigned short* __restrict__ decEW, const float* __restrict__ dec_eb,
    const unsigned short* __restrict__ decWih, const unsigned short* __restrict__ decWhh,
    const float* __restrict__ dec_bih, const float* __restrict__ dec_bhh,
    const float* __restrict__ outW, const float* __restrict__ outb,
    float* __restrict__ out)
{
    __shared__ __align__(16) unsigned short ls_h[MROW * HD];  // h, bf16, swizzled
    __shared__ __align__(16) unsigned short ls_a[MROW * HD];  // gru input, bf16, swizzled
    __shared__ float ls_ow[4 * HD];   // out_W
    __shared__ float ls_ew[HD * 4];   // enc_embed_W
    __shared__ float ls_eb[HD];       // enc_embed_b

    const int tid  = threadIdx.x;
    const int lane = tid & 63;
    const int wv   = tid >> 6;      // wave 0..7
    const int cb   = wv * 32;       // this wave's column base within H
    const int lrow = lane & 15;     // A-row / B-col within a 16x16 tile
    const int kgrp = lane >> 4;     // 0..3 (k-group of 8)
    const int nbase = blockIdx.x * MROW;

    for (int i = tid; i < 4 * HD; i += NTHR) ls_ow[i] = outW[i];
    for (int i = tid; i < HD * 4; i += NTHR) ls_ew[i] = eW[i];
    for (int i = tid; i < HD;     i += NTHR) ls_eb[i] = eb[i];

    // h fp32 carry, C/D fragment layout: row = rt*16 + kgrp*4 + r, col = cb + ct*16 + lrow
    f32x4 hreg[2][4];
    #pragma unroll
    for (int ct = 0; ct < 2; ++ct)
        #pragma unroll
        for (int rt = 0; rt < 4; ++rt)
            hreg[ct][rt] = f32x4{0.f, 0.f, 0.f, 0.f};

    // gate accumulators: r, z, inn (from x-side), hn (from h-side)
    f32x4 accR[2][4], accZ[2][4], accN1[2][4], accN2[2][4];

    auto zero_acc = [&]() {
        #pragma unroll
        for (int ct = 0; ct < 2; ++ct)
            #pragma unroll
            for (int rt = 0; rt < 4; ++rt) {
                accR[ct][rt]  = f32x4{0.f, 0.f, 0.f, 0.f};
                accZ[ct][rt]  = f32x4{0.f, 0.f, 0.f, 0.f};
                accN1[ct][rt] = f32x4{0.f, 0.f, 0.f, 0.f};
                accN2[ct][rt] = f32x4{0.f, 0.f, 0.f, 0.f};
            }
    };

    // One gate matmul phase: acc{R,Z,T} += A(ls) @ W^T for this wave's columns.
    // W is [768][256] bf16 row-major; segments r(+0), z(+256), n(+512).
    auto gates_phase = [&](const unsigned short* __restrict__ ls,
                           const unsigned short* __restrict__ W,
                           f32x4 (&accT)[2][4]) {
        #pragma unroll 2
        for (int kk = 0; kk < 8; ++kk) {
            const int k = kk * 32 + kgrp * 8;
            const int c = kk * 4 + kgrp;  // 8-elem chunk index
            bf16x8 a[4];
            #pragma unroll
            for (int rt = 0; rt < 4; ++rt) {
                int row = rt * 16 + lrow;
                a[rt] = *(const bf16x8*)((const char*)ls + row * 512 + ((c ^ (row & 7)) << 4));
            }
            const unsigned short* w0 = W + (size_t)(cb + lrow) * HD + k;
            bf16x8 b0 = *(const bf16x8*)(w0);              // r,  ct0
            bf16x8 b1 = *(const bf16x8*)(w0 + 16 * HD);    // r,  ct1
            bf16x8 b2 = *(const bf16x8*)(w0 + 256 * HD);   // z,  ct0
            bf16x8 b3 = *(const bf16x8*)(w0 + 272 * HD);   // z,  ct1
            bf16x8 b4 = *(const bf16x8*)(w0 + 512 * HD);   // n,  ct0
            bf16x8 b5 = *(const bf16x8*)(w0 + 528 * HD);   // n,  ct1
            #pragma unroll
            for (int rt = 0; rt < 4; ++rt) {
                accR[0][rt] = MFMA16(a[rt], b0, accR[0][rt], 0, 0, 0);
                accR[1][rt] = MFMA16(a[rt], b1, accR[1][rt], 0, 0, 0);
                accZ[0][rt] = MFMA16(a[rt], b2, accZ[0][rt], 0, 0, 0);
                accZ[1][rt] = MFMA16(a[rt], b3, accZ[1][rt], 0, 0, 0);
                accT[0][rt] = MFMA16(a[rt], b4, accT[0][rt], 0, 0, 0);
                accT[1][rt] = MFMA16(a[rt], b5, accT[1][rt], 0, 0, 0);
            }
        }
    };

    float bR[2], bZ[2], bN[2], bH[2];
    auto load_biases = [&](const float* bih, const float* bhh) {
        #pragma unroll
        for (int ct = 0; ct < 2; ++ct) {
            int col = cb + ct * 16 + lrow;
            bR[ct] = bih[col] + bhh[col];
            bZ[ct] = bih[HD + col] + bhh[HD + col];
            bN[ct] = bih[2 * HD + col];
            bH[ct] = bhh[2 * HD + col];
        }
    };

    auto gru_update = [&]() {
        #pragma unroll
        for (int ct = 0; ct < 2; ++ct)
            #pragma unroll
            for (int rt = 0; rt < 4; ++rt)
                #pragma unroll
                for (int r = 0; r < 4; ++r) {
                    float rr = 1.f / (1.f + __expf(-(accR[ct][rt][r] + bR[ct])));
                    float zz = 1.f / (1.f + __expf(-(accZ[ct][rt][r] + bZ[ct])));
                    float pre = accN1[ct][rt][r] + bN[ct] + rr * (accN2[ct][rt][r] + bH[ct]);
                    float nn = 2.f / (1.f + __expf(-2.f * pre)) - 1.f;  // tanh
                    float ho = hreg[ct][rt][r];
                    hreg[ct][rt][r] = (1.f - zz) * nn + zz * ho;
                }
    };

    auto write_h = [&]() {
        #pragma unroll
        for (int ct = 0; ct < 2; ++ct)
            #pragma unroll
            for (int rt = 0; rt < 4; ++rt)
                #pragma unroll
                for (int r = 0; r < 4; ++r) {
                    int row = rt * 16 + kgrp * 4 + r;
                    int col = cb + ct * 16 + lrow;
                    *(unsigned short*)((char*)ls_h + swz(row, col)) = f2bf(hreg[ct][rt][r]);
                }
    };

    // enc_embed: ls_a[row][col] = relu(x[n,t,:] . eW[col,:] + eb[col]) as bf16
    auto embed_step = [&](int t) {
        int row = tid & 63;
        int c0  = (tid >> 6) * 32;
        const float* xp = x + ((size_t)(nbase + row) * TENC + t) * 4;
        float x0 = xp[0], x1 = xp[1], x2 = xp[2], x3 = xp[3];
        #pragma unroll 8
        for (int j = 0; j < 32; ++j) {
            int col = c0 + j;
            const float* wp = &ls_ew[col * 4];
            float v = ls_eb[col] + x0 * wp[0] + x1 * wp[1] + x2 * wp[2] + x3 * wp[3];
            v = fmaxf(v, 0.f);
            *(unsigned short*)((char*)ls_a + swz(row, col)) = f2bf(v);
        }
    };

    float deb[2];

    // dec_in = relu(h @ dec_embed_W^T + dec_embed_b) -> ls_a
    auto dec_embed_phase = [&]() {
        f32x4 a2[2][4];
        #pragma unroll
        for (int ct = 0; ct < 2; ++ct)
            #pragma unroll
            for (int rt = 0; rt < 4; ++rt)
                a2[ct][rt] = f32x4{0.f, 0.f, 0.f, 0.f};
        #pragma unroll 2
        for (int kk = 0; kk < 8; ++kk) {
            const int k = kk * 32 + kgrp * 8;
            const int c = kk * 4 + kgrp;
            bf16x8 a[4];
            #pragma unroll
            for (int rt = 0; rt < 4; ++rt) {
                int row = rt * 16 + lrow;
                a[rt] = *(const bf16x8*)((const char*)ls_h + row * 512 + ((c ^ (row & 7)) << 4));
            }
            const unsigned short* w0 = decEW + (size_t)(cb + lrow) * HD + k;
            bf16x8 b0 = *(const bf16x8*)(w0);
            bf16x8 b1 = *(const bf16x8*)(w0 + 16 * HD);
            #pragma unroll
            for (int rt = 0; rt < 4; ++rt) {
                a2[0][rt] = MFMA16(a[rt], b0, a2[0][rt], 0, 0, 0);
                a2[1][rt] = MFMA16(a[rt], b1, a2[1][rt], 0, 0, 0);
            }
        }
        #pragma unroll
        for (int ct = 0; ct < 2; ++ct)
            #pragma unroll
            for (int rt = 0; rt < 4; ++rt)
                #pragma unroll
                for (int r = 0; r < 4; ++r) {
                    int row = rt * 16 + kgrp * 4 + r;
                    int col = cb + ct * 16 + lrow;
                    float v = a2[ct][rt][r] + deb[ct];
                    v = fmaxf(v, 0.f);
                    *(unsigned short*)((char*)ls_a + swz(row, col)) = f2bf(v);
                }
    };

    auto out_layer = [&](int t) {
        if (tid < 256) {
            int row = tid >> 2, o = tid & 3;
            const float* wo = &ls_ow[o * HD];
            float s = outb[o];
            #pragma unroll 4
            for (int cc = 0; cc < HD; ++cc) {
                float hv = bf2f(*(const unsigned short*)((const char*)ls_h + swz(row, cc)));
                s = fmaf(hv, wo[cc], s);
            }
            out[((size_t)(nbase + row) * PLEN + t) * 4 + o] = s;
        }
    };

    // ---- prologue ----
    load_biases(enc_bih, enc_bhh);
    __syncthreads();            // ls_ew/ls_eb staged
    embed_step(0);
    write_h();                  // h0 = 0
    __syncthreads();

    // ---- encoder ----
    for (int t = 0; t < TENC; ++t) {
        zero_acc();
        gates_phase(ls_a, encWih, accN1);   // gi: r,z,inn
        gates_phase(ls_h, encWhh, accN2);   // gh: r,z,hn
        gru_update();
        __syncthreads();                    // all reads of ls_a/ls_h done
        write_h();
        if (t + 1 < TENC) embed_step(t + 1);
        __syncthreads();
    }

    // ---- decoder prologue ----
    load_biases(dec_bih, dec_bhh);
    #pragma unroll
    for (int ct = 0; ct < 2; ++ct) deb[ct] = dec_eb[cb + ct * 16 + lrow];
    dec_embed_phase();                      // dec_in0 from h_enc
    __syncthreads();

    // ---- decoder ----
    for (int t = 0; t < PLEN; ++t) {
        zero_acc();
        gates_phase(ls_a, decWih, accN1);
        gates_phase(ls_h, decWhh, accN2);
        gru_update();
        __syncthreads();                    // reads of ls_a/ls_h done
        write_h();
        __syncthreads();                    // new h visible
        dec_embed_phase();                  // next dec_in -> ls_a
        out_layer(t);                       // out_t from new h
        __syncthreads();                    // ls_a ready for next step
    }
}

extern "C" void kernel_launch(void* const* d_in, const int* in_sizes, int n_in,
                              void* d_out, int out_size, void* d_ws, size_t ws_size,
                              hipStream_t stream) {
    const float* x       = (const float*)d_in[0];
    const float* eW      = (const float*)d_in[1];
    const float* eb      = (const float*)d_in[2];
    const float* encWih  = (const float*)d_in[3];
    const float* encWhh  = (const float*)d_in[4];
    const float* enc_bih = (const float*)d_in[5];
    const float* enc_bhh = (const float*)d_in[6];
    const float* decEWf  = (const float*)d_in[7];
    const float* dec_eb  = (const float*)d_in[8];
    const float* decWihf = (const float*)d_in[9];
    const float* decWhhf = (const float*)d_in[10];
    const float* dec_bih = (const float*)d_in[11];
    const float* dec_bhh = (const float*)d_in[12];
    const float* outW    = (const float*)d_in[13];
    const float* outb    = (const float*)d_in[14];

    unsigned short* ws = (unsigned short*)d_ws;
    unsigned short* bWih_e = ws;                 // 3*H*H = 196608 each
    unsigned short* bWhh_e = ws + 196608;
    unsigned short* bWih_d = ws + 2 * 196608;
    unsigned short* bWhh_d = ws + 3 * 196608;
    unsigned short* bEW_d  = ws + 4 * 196608;    // H*H = 65536

    const int n1 = 3 * HD * HD;
    const int n2 = HD * HD;
    cvt_bf16_kernel<<<(n1 + 255) / 256, 256, 0, stream>>>(encWih,  bWih_e, n1);
    cvt_bf16_kernel<<<(n1 + 255) / 256, 256, 0, stream>>>(encWhh,  bWhh_e, n1);
    cvt_bf16_kernel<<<(n1 + 255) / 256, 256, 0, stream>>>(decWihf, bWih_d, n1);
    cvt_bf16_kernel<<<(n1 + 255) / 256, 256, 0, stream>>>(decWhhf, bWhh_d, n1);
    cvt_bf16_kernel<<<(n2 + 255) / 256, 256, 0, stream>>>(decEWf,  bEW_d,  n2);

    gru_main<<<32768 / MROW, NTHR, 0, stream>>>(
        x, eW, eb, bWih_e, bWhh_e, enc_bih, enc_bhh,
        bEW_d, dec_eb, bWih_d, bWhh_d, dec_bih, dec_bhh,
        outW, outb, (float*)d_out);
}